// Round 13
// baseline (83284.943 us; speedup 1.0000x reference)
//
#include <hip/hip_runtime.h>
#include <math.h>

static constexpr int NB  = 1024;
static constexpr int NS  = 100;
static constexpr int NH  = 128;
static constexpr int GPB = 4;           // batches per block (1 weight read -> 4 batches)
static constexpr int NTHR = 256;
static constexpr int NBLK = NB / GPB;   // 256 blocks = 1 per CU

static constexpr int OUT_MU = 0;
static constexpr int OUT_LV = NB * NS;
static constexpr int OUT_Z  = 2 * NB * NS;
static constexpr int OUT_TI = 3 * NB * NS;
static constexpr int OUT_LP = 4 * NB * NS;

#define NEGF (-3.4e38f)

// ---- chunked register-prefetch f32 dot helpers ----
// Loads CH float4 words into registers (all in flight), then FMAs.
// Per-accumulator order identical to R11's dot4f (c ascending) => bitwise same.
template<int CH>
__device__ __forceinline__ void d4ch(const float4* __restrict__ W,
        const float* __restrict__ x0, const float* __restrict__ x1,
        const float* __restrict__ x2, const float* __restrict__ x3,
        float& a0, float& a1, float& a2, float& a3)
{
    float4 wr[CH];
    #pragma unroll
    for (int c = 0; c < CH; ++c) wr[c] = W[c];
    #pragma unroll
    for (int c = 0; c < CH; ++c) {
        float4 u = wr[c];
        int k = 4 * c;
        a0 = fmaf(u.x, x0[k], a0); a0 = fmaf(u.y, x0[k+1], a0); a0 = fmaf(u.z, x0[k+2], a0); a0 = fmaf(u.w, x0[k+3], a0);
        a1 = fmaf(u.x, x1[k], a1); a1 = fmaf(u.y, x1[k+1], a1); a1 = fmaf(u.z, x1[k+2], a1); a1 = fmaf(u.w, x1[k+3], a1);
        a2 = fmaf(u.x, x2[k], a2); a2 = fmaf(u.y, x2[k+1], a2); a2 = fmaf(u.z, x2[k+2], a2); a2 = fmaf(u.w, x2[k+3], a2);
        a3 = fmaf(u.x, x3[k], a3); a3 = fmaf(u.y, x3[k+1], a3); a3 = fmaf(u.z, x3[k+2], a3); a3 = fmaf(u.w, x3[k+3], a3);
    }
}

template<int C4>
__device__ __forceinline__ void dot4f(const float* __restrict__ w,
        const float* __restrict__ x0, const float* __restrict__ x1,
        const float* __restrict__ x2, const float* __restrict__ x3,
        float& r0, float& r1, float& r2, float& r3)
{
    const float4* W = reinterpret_cast<const float4*>(w);
    float a0 = 0.f, a1 = 0.f, a2 = 0.f, a3 = 0.f;
    constexpr int NCH = C4 / 32;
    constexpr int REM = C4 % 32;
    #pragma unroll
    for (int b = 0; b < NCH; ++b)
        d4ch<32>(W + 32 * b, x0 + 128 * b, x1 + 128 * b, x2 + 128 * b, x3 + 128 * b, a0, a1, a2, a3);
    if constexpr (REM > 0)
        d4ch<REM>(W + 32 * NCH, x0 + 128 * NCH, x1 + 128 * NCH, x2 + 128 * NCH, x3 + 128 * NCH, a0, a1, a2, a3);
    r0 = a0; r1 = a1; r2 = a2; r3 = a3;
}

template<int CH>
__device__ __forceinline__ void d2ch(const float4* __restrict__ W,
        const float* __restrict__ x0, const float* __restrict__ x1,
        float& a0, float& a1)
{
    float4 wr[CH];
    #pragma unroll
    for (int c = 0; c < CH; ++c) wr[c] = W[c];
    #pragma unroll
    for (int c = 0; c < CH; ++c) {
        float4 u = wr[c];
        int k = 4 * c;
        a0 = fmaf(u.x, x0[k], a0); a0 = fmaf(u.y, x0[k+1], a0); a0 = fmaf(u.z, x0[k+2], a0); a0 = fmaf(u.w, x0[k+3], a0);
        a1 = fmaf(u.x, x1[k], a1); a1 = fmaf(u.y, x1[k+1], a1); a1 = fmaf(u.z, x1[k+2], a1); a1 = fmaf(u.w, x1[k+3], a1);
    }
}

template<int C4>
__device__ __forceinline__ void dot2f(const float* __restrict__ w,
        const float* __restrict__ x0, const float* __restrict__ x1, float& r0, float& r1)
{
    const float4* W = reinterpret_cast<const float4*>(w);
    float a0 = 0.f, a1 = 0.f;
    constexpr int NCH = C4 / 32;
    constexpr int REM = C4 % 32;
    #pragma unroll
    for (int b = 0; b < NCH; ++b)
        d2ch<32>(W + 32 * b, x0 + 128 * b, x1 + 128 * b, a0, a1);
    if constexpr (REM > 0)
        d2ch<REM>(W + 32 * NCH, x0 + 128 * NCH, x1 + 128 * NCH, a0, a1);
    r0 = a0; r1 = a1;
}

// Strided column dot, f64 sequential accumulation in R11's exact order (k
// ascending), weights prefetched 16-at-a-time into registers.
__device__ __forceinline__ void qcol2(const float* __restrict__ col,
        const float* __restrict__ v0, const float* __restrict__ v1,
        double& r0, double& r1)
{
    double a0 = 0.0, a1 = 0.0;
    #pragma unroll
    for (int kb = 0; kb < NH; kb += 16) {
        float w[16];
        #pragma unroll
        for (int i = 0; i < 16; ++i) w[i] = col[(size_t)(kb + i) * NH];
        #pragma unroll
        for (int i = 0; i < 16; ++i) {
            a0 = fma((double)w[i], (double)v0[kb + i], a0);
            a1 = fma((double)w[i], (double)v1[kb + i], a1);
        }
    }
    r0 = a0; r1 = a1;
}

// f64-accum dot (mu/lv epilogue) — R11 verbatim.
template<int C4>
__device__ __forceinline__ double dotwd(const float* __restrict__ w, const float* __restrict__ x)
{
    const float4* W = reinterpret_cast<const float4*>(w);
    double a = 0.0;
    #pragma unroll 8
    for (int c = 0; c < C4; ++c) {
        float4 u = W[c];
        const float* p = x + 4 * c;
        a = fma((double)u.x, (double)p[0], a);
        a = fma((double)u.y, (double)p[1], a);
        a = fma((double)u.z, (double)p[2], a);
        a = fma((double)u.w, (double)p[3], a);
    }
    return a;
}

// GRU nonlinearity (f64 internals, f32 storage) — R11 verbatim.
__device__ __forceinline__ void gruc(const float* __restrict__ bih, const float* __restrict__ bhh,
        const float* __restrict__ pa, const float* __restrict__ pb, float* __restrict__ h, int j)
{
    double r = 1.0 / (1.0 + exp(-(((double)pa[j]        + (double)bih[j])        + ((double)pb[j]        + (double)bhh[j]))));
    double z = 1.0 / (1.0 + exp(-(((double)pa[NH + j]   + (double)bih[NH + j])   + ((double)pb[NH + j]   + (double)bhh[NH + j]))));
    double n = tanh(((double)pa[2*NH + j] + (double)bih[2*NH + j]) + r * ((double)pb[2*NH + j] + (double)bhh[2*NH + j]));
    h[j] = (float)((1.0 - z) * n + z * (double)h[j]);
}

__global__ __launch_bounds__(NTHR, 1) void vae_v13(
    const float* __restrict__ instance, const int* __restrict__ sol1,
    const int* __restrict__ sol2, const float* __restrict__ eps,
    const float* __restrict__ emb_i_W, const float* __restrict__ emb_i_b,
    const float* __restrict__ emb_r_W, const float* __restrict__ emb_r_b,
    const float* __restrict__ attn_W, const float* __restrict__ attn_v,
    const float* __restrict__ gru_Wih, const float* __restrict__ gru_Whh,
    const float* __restrict__ gru_bih, const float* __restrict__ gru_bhh,
    const float* __restrict__ grud_Wih, const float* __restrict__ grud_Whh,
    const float* __restrict__ grud_bih, const float* __restrict__ grud_bhh,
    const float* __restrict__ efc1_W, const float* __restrict__ efc1_b,
    const float* __restrict__ efc2_W, const float* __restrict__ efc2_b,
    const float* __restrict__ ptr_W, const float* __restrict__ ptr_v,
    const float* __restrict__ pfc1_W, const float* __restrict__ pfc1_b,
    const float* __restrict__ pfc2_W, const float* __restrict__ pfc2_b,
    float* __restrict__ out)
{
    __shared__ float  s_x[GPB][360];            // enc: [ref|ctx]; dec: [ctx|Z|ref]
    __shared__ float  s_h1[GPB][NH], s_h2[GPB][NH], s_fco[GPB][NH];
    __shared__ float  s_fch[GPB][256];
    __shared__ float  s_pa[GPB][3 * NH], s_pb[GPB][3 * NH];
    __shared__ double s_qh[GPB][NH];            // Ab + rnn-side q (f64 — logit path)
    __shared__ double dA0a[NH], dA1a[NH], dAba[NH];   // attn collapse (f64)
    __shared__ double dA0p[NH], dA1p[NH], dAbp[NH];   // ptr collapse (f64)
    __shared__ float  s_lg[GPB][NS], s_a[GPB][NS];
    __shared__ float  s_c0[GPB][NS], s_c1[GPB][NS], s_msk[GPB][NS];
    __shared__ float  t_wi0[NH], t_wi1[NH], t_bi[NH];
    __shared__ float  t_wr0[NH], t_wr1[NH], t_br[NH];
    __shared__ float  t_va[NH], t_vp[NH];
    __shared__ float  s_red[GPB][16];           // f32 max partials
    __shared__ double s_redd[GPB][16];          // f64 sum partials
    __shared__ int    s_ri[GPB][16];
    __shared__ float  s_mx[GPB];
    __shared__ double s_se[GPB];
    __shared__ float  s_rc0[GPB], s_rc1[GPB];

    const int tid = threadIdx.x;
    const int bbase = blockIdx.x * GPB;
    const int j = tid & (NH - 1);
    const int half = tid >> 7;
    const int g0 = half, g1 = half + 2;

    // ---------- init ----------
    if (tid < NH) {
        t_wi0[tid] = emb_i_W[2*tid]; t_wi1[tid] = emb_i_W[2*tid+1]; t_bi[tid] = emb_i_b[tid];
        t_wr0[tid] = emb_r_W[2*tid]; t_wr1[tid] = emb_r_W[2*tid+1]; t_br[tid] = emb_r_b[tid];
        t_va[tid] = attn_v[tid]; t_vp[tid] = ptr_v[tid];
    }
    for (int i = tid; i < GPB * NS; i += NTHR) {
        int g = i / NS, s = i - g * NS;
        s_c0[g][s] = instance[(size_t)((bbase + g) * NS + s) * 2 + 0];
        s_c1[g][s] = instance[(size_t)((bbase + g) * NS + s) * 2 + 1];
    }
    s_h1[g0][j] = 0.f; s_h1[g1][j] = 0.f;
    s_h2[g0][j] = 0.f; s_h2[g1][j] = 0.f;
    __syncthreads();
    {   // collapse tables: f64 exact algebra (R11 verbatim)
        const float* Wm = (half == 0) ? attn_W : ptr_W;
        double a0 = 0.0, a1 = 0.0, ab = 0.0;
        for (int k = 0; k < NH; ++k) {
            double wv = (double)Wm[(size_t)k * NH + j];
            a0 = fma((double)t_wi0[k], wv, a0);
            a1 = fma((double)t_wi1[k], wv, a1);
            ab = fma((double)t_bi[k],  wv, ab);
        }
        if (half == 0) { dA0a[j] = a0; dA1a[j] = a1; dAba[j] = ab; }
        else           { dA0p[j] = a0; dA1p[j] = a1; dAbp[j] = ab; }
    }
    {   // initial encoder ref_h
        int sp0 = sol1[(bbase + g0) * NS + 0];
        int sp1 = sol1[(bbase + g1) * NS + 0];
        s_x[g0][j] = fmaf(s_c0[g0][sp0], t_wr0[j], fmaf(s_c1[g0][sp0], t_wr1[j], t_br[j]));
        s_x[g1][j] = fmaf(s_c0[g1][sp1], t_wr0[j], fmaf(s_c1[g1][sp1], t_wr1[j], t_br[j]));
    }
    __syncthreads();

    // ---------- encoder ----------
    for (int t = 1; t < NS; ++t) {
        if (half == 0) {    // GRU1 x-side (register-prefetch rows)
            float r0, r1, r2, r3;
            dot4f<32>(gru_Wih + (size_t)j          * NH, s_x[0], s_x[1], s_x[2], s_x[3], r0, r1, r2, r3);
            s_pa[0][j] = r0; s_pa[1][j] = r1; s_pa[2][j] = r2; s_pa[3][j] = r3;
            dot4f<32>(gru_Wih + (size_t)(NH + j)   * NH, s_x[0], s_x[1], s_x[2], s_x[3], r0, r1, r2, r3);
            s_pa[0][NH + j] = r0; s_pa[1][NH + j] = r1; s_pa[2][NH + j] = r2; s_pa[3][NH + j] = r3;
            dot4f<32>(gru_Wih + (size_t)(2*NH + j) * NH, s_x[0], s_x[1], s_x[2], s_x[3], r0, r1, r2, r3);
            s_pa[0][2*NH + j] = r0; s_pa[1][2*NH + j] = r1; s_pa[2][2*NH + j] = r2; s_pa[3][2*NH + j] = r3;
        } else {            // GRU1 h-side
            float r0, r1, r2, r3;
            dot4f<32>(gru_Whh + (size_t)j          * NH, s_h1[0], s_h1[1], s_h1[2], s_h1[3], r0, r1, r2, r3);
            s_pb[0][j] = r0; s_pb[1][j] = r1; s_pb[2][j] = r2; s_pb[3][j] = r3;
            dot4f<32>(gru_Whh + (size_t)(NH + j)   * NH, s_h1[0], s_h1[1], s_h1[2], s_h1[3], r0, r1, r2, r3);
            s_pb[0][NH + j] = r0; s_pb[1][NH + j] = r1; s_pb[2][NH + j] = r2; s_pb[3][NH + j] = r3;
            dot4f<32>(gru_Whh + (size_t)(2*NH + j) * NH, s_h1[0], s_h1[1], s_h1[2], s_h1[3], r0, r1, r2, r3);
            s_pb[0][2*NH + j] = r0; s_pb[1][2*NH + j] = r1; s_pb[2][2*NH + j] = r2; s_pb[3][2*NH + j] = r3;
        }
        __syncthreads();
        gruc(gru_bih, gru_bhh, s_pa[g0], s_pb[g0], s_h1[g0], j);
        gruc(gru_bih, gru_bhh, s_pa[g1], s_pb[g1], s_h1[g1], j);
        __syncthreads();
        {   // q = Ab + h1 . attn_W[128:256] columns (f64 sequential, R11 order)
            double a0, a1;
            qcol2(attn_W + (size_t)NH * NH + j, s_h1[g0], s_h1[g1], a0, a1);
            s_qh[g0][j] = dAba[j] + a0;
            s_qh[g1][j] = dAba[j] + a1;
        }
        __syncthreads();
        if (j < NS) {   // relu head logits (f64 pre/accum, R11 verbatim)
            double c00 = (double)s_c0[g0][j], c10 = (double)s_c1[g0][j];
            double c01 = (double)s_c0[g1][j], c11 = (double)s_c1[g1][j];
            double acc0 = 0.0, acc1 = 0.0;
            for (int h = 0; h < NH; ++h) {
                double A0 = dA0a[h], A1 = dA1a[h], v = (double)t_va[h];
                double p0 = fma(c00, A0, fma(c10, A1, s_qh[g0][h]));
                double p1 = fma(c01, A0, fma(c11, A1, s_qh[g1][h]));
                acc0 = fma(fmax(p0, 0.0), v, acc0);
                acc1 = fma(fmax(p1, 0.0), v, acc1);
            }
            s_lg[g0][j] = (float)acc0;
            s_lg[g1][j] = (float)acc1;
        }
        __syncthreads();
        if (j < 16) {   // segmented max
            float m0 = NEGF, m1 = NEGF;
            for (int s = j; s < NS; s += 16) { m0 = fmaxf(m0, s_lg[g0][s]); m1 = fmaxf(m1, s_lg[g1][s]); }
            s_red[g0][j] = m0; s_red[g1][j] = m1;
        }
        __syncthreads();
        if (tid < GPB) {
            float m = NEGF;
            for (int i = 0; i < 16; ++i) m = fmaxf(m, s_red[tid][i]);
            s_mx[tid] = m;
        }
        __syncthreads();
        if (j < NS) {   // exps: f64 exp narrowed to f32 (R11 verbatim)
            s_a[g0][j] = (float)exp((double)s_lg[g0][j] - (double)s_mx[g0]);
            s_a[g1][j] = (float)exp((double)s_lg[g1][j] - (double)s_mx[g1]);
        }
        __syncthreads();
        if (j < 16) {   // segmented f64 sum
            double t0 = 0.0, t1 = 0.0;
            for (int s = j; s < NS; s += 16) { t0 += (double)s_a[g0][s]; t1 += (double)s_a[g1][s]; }
            s_redd[g0][j] = t0; s_redd[g1][j] = t1;
        }
        __syncthreads();
        if (tid < GPB) {
            double se = 0.0;
            for (int i = 0; i < 16; ++i) se += s_redd[tid][i];
            s_se[tid] = se;
        }
        __syncthreads();
        if (j < NS) {   // normalize (R11 verbatim)
            s_a[g0][j] = (float)((double)s_a[g0][j] / s_se[g0]);
            s_a[g1][j] = (float)((double)s_a[g1][j] / s_se[g1]);
        }
        __syncthreads();
        {   // context (f64 accum, R11 verbatim) + new ref_h
            float w0 = t_wi0[j], w1 = t_wi1[j], bb = t_bi[j];
            double a0 = 0.0, a1 = 0.0;
            for (int s = 0; s < NS; ++s) {
                float ih0 = fmaf(s_c0[g0][s], w0, fmaf(s_c1[g0][s], w1, bb));
                float ih1 = fmaf(s_c0[g1][s], w0, fmaf(s_c1[g1][s], w1, bb));
                a0 += (double)s_a[g0][s] * (double)ih0;
                a1 += (double)s_a[g1][s] * (double)ih1;
            }
            s_x[g0][NH + j] = (float)a0;
            s_x[g1][NH + j] = (float)a1;
            int sp0 = sol1[(bbase + g0) * NS + t];
            int sp1 = sol1[(bbase + g1) * NS + t];
            s_x[g0][j] = fmaf(s_c0[g0][sp0], t_wr0[j], fmaf(s_c1[g0][sp0], t_wr1[j], t_br[j]));
            s_x[g1][j] = fmaf(s_c0[g1][sp1], t_wr0[j], fmaf(s_c1[g1][sp1], t_wr1[j], t_br[j]));
        }
        __syncthreads();
        if (half == 0) {    // GRUd x-side (K=256)
            float r0, r1, r2, r3;
            dot4f<64>(grud_Wih + (size_t)j          * 256, s_x[0], s_x[1], s_x[2], s_x[3], r0, r1, r2, r3);
            s_pa[0][j] = r0; s_pa[1][j] = r1; s_pa[2][j] = r2; s_pa[3][j] = r3;
            dot4f<64>(grud_Wih + (size_t)(NH + j)   * 256, s_x[0], s_x[1], s_x[2], s_x[3], r0, r1, r2, r3);
            s_pa[0][NH + j] = r0; s_pa[1][NH + j] = r1; s_pa[2][NH + j] = r2; s_pa[3][NH + j] = r3;
            dot4f<64>(grud_Wih + (size_t)(2*NH + j) * 256, s_x[0], s_x[1], s_x[2], s_x[3], r0, r1, r2, r3);
            s_pa[0][2*NH + j] = r0; s_pa[1][2*NH + j] = r1; s_pa[2][2*NH + j] = r2; s_pa[3][2*NH + j] = r3;
        } else {            // GRUd h-side
            float r0, r1, r2, r3;
            dot4f<32>(grud_Whh + (size_t)j          * NH, s_h2[0], s_h2[1], s_h2[2], s_h2[3], r0, r1, r2, r3);
            s_pb[0][j] = r0; s_pb[1][j] = r1; s_pb[2][j] = r2; s_pb[3][j] = r3;
            dot4f<32>(grud_Whh + (size_t)(NH + j)   * NH, s_h2[0], s_h2[1], s_h2[2], s_h2[3], r0, r1, r2, r3);
            s_pb[0][NH + j] = r0; s_pb[1][NH + j] = r1; s_pb[2][NH + j] = r2; s_pb[3][NH + j] = r3;
            dot4f<32>(grud_Whh + (size_t)(2*NH + j) * NH, s_h2[0], s_h2[1], s_h2[2], s_h2[3], r0, r1, r2, r3);
            s_pb[0][2*NH + j] = r0; s_pb[1][2*NH + j] = r1; s_pb[2][2*NH + j] = r2; s_pb[3][2*NH + j] = r3;
        }
        __syncthreads();
        gruc(grud_bih, grud_bhh, s_pa[g0], s_pb[g0], s_h2[g0], j);
        gruc(grud_bih, grud_bhh, s_pa[g1], s_pb[g1], s_h2[g1], j);
        __syncthreads();
    }

    // ---------- epilogue: mu, lv, Z (f64, R11 verbatim) ----------
    for (int idx = tid; idx < GPB * NS; idx += NTHR) {
        int g = idx / NS, s = idx - g * NS, b = bbase + g;
        double mu = dotwd<32>(efc1_W + (size_t)s * NH, s_h2[g]) + (double)efc1_b[s];
        double lv = dotwd<32>(efc2_W + (size_t)s * NH, s_h2[g]) + (double)efc2_b[s];
        double z  = mu + (double)eps[(size_t)b * NS + s] * exp(0.5 * lv);
        out[OUT_MU + b * NS + s] = (float)mu;
        out[OUT_LV + b * NS + s] = (float)lv;
        out[OUT_Z  + b * NS + s] = (float)z;
        s_x[g][NH + s] = (float)z;   // decoder Z slot [128..227]
    }
    for (int i = tid; i < GPB * NS; i += NTHR) {
        int g = i / NS, s = i - g * NS;
        s_msk[g][s] = 1.f;
    }
    s_h1[g0][j] = 0.f; s_h1[g1][j] = 0.f;
    __syncthreads();
    if (tid < GPB) {
        int b = bbase + tid;
        int s0 = sol2[b * NS + 0];
        s_msk[tid][s0] = 0.f;
        s_rc0[tid] = s_c0[tid][s0];
        s_rc1[tid] = s_c1[tid][s0];
        out[OUT_TI + b * NS + 0] = (float)s0;
    }
    __syncthreads();

    // ---------- decoder ----------
    for (int t = 1; t < NS; ++t) {
        s_x[g0][228 + j] = fmaf(s_rc0[g0], t_wr0[j], fmaf(s_rc1[g0], t_wr1[j], t_br[j]));
        s_x[g1][228 + j] = fmaf(s_rc0[g1], t_wr0[j], fmaf(s_rc1[g1], t_wr1[j], t_br[j]));
        __syncthreads();
        if (half == 0) {    // GRU1 x-side on ref
            float r0, r1, r2, r3;
            dot4f<32>(gru_Wih + (size_t)j          * NH, s_x[0]+228, s_x[1]+228, s_x[2]+228, s_x[3]+228, r0, r1, r2, r3);
            s_pa[0][j] = r0; s_pa[1][j] = r1; s_pa[2][j] = r2; s_pa[3][j] = r3;
            dot4f<32>(gru_Wih + (size_t)(NH + j)   * NH, s_x[0]+228, s_x[1]+228, s_x[2]+228, s_x[3]+228, r0, r1, r2, r3);
            s_pa[0][NH + j] = r0; s_pa[1][NH + j] = r1; s_pa[2][NH + j] = r2; s_pa[3][NH + j] = r3;
            dot4f<32>(gru_Wih + (size_t)(2*NH + j) * NH, s_x[0]+228, s_x[1]+228, s_x[2]+228, s_x[3]+228, r0, r1, r2, r3);
            s_pa[0][2*NH + j] = r0; s_pa[1][2*NH + j] = r1; s_pa[2][2*NH + j] = r2; s_pa[3][2*NH + j] = r3;
        } else {
            float r0, r1, r2, r3;
            dot4f<32>(gru_Whh + (size_t)j          * NH, s_h1[0], s_h1[1], s_h1[2], s_h1[3], r0, r1, r2, r3);
            s_pb[0][j] = r0; s_pb[1][j] = r1; s_pb[2][j] = r2; s_pb[3][j] = r3;
            dot4f<32>(gru_Whh + (size_t)(NH + j)   * NH, s_h1[0], s_h1[1], s_h1[2], s_h1[3], r0, r1, r2, r3);
            s_pb[0][NH + j] = r0; s_pb[1][NH + j] = r1; s_pb[2][NH + j] = r2; s_pb[3][NH + j] = r3;
            dot4f<32>(gru_Whh + (size_t)(2*NH + j) * NH, s_h1[0], s_h1[1], s_h1[2], s_h1[3], r0, r1, r2, r3);
            s_pb[0][2*NH + j] = r0; s_pb[1][2*NH + j] = r1; s_pb[2][2*NH + j] = r2; s_pb[3][2*NH + j] = r3;
        }
        __syncthreads();
        gruc(gru_bih, gru_bhh, s_pa[g0], s_pb[g0], s_h1[g0], j);
        gruc(gru_bih, gru_bhh, s_pa[g1], s_pb[g1], s_h1[g1], j);
        __syncthreads();
        {   // q (attn, f64 sequential, R11 order)
            double a0, a1;
            qcol2(attn_W + (size_t)NH * NH + j, s_h1[g0], s_h1[g1], a0, a1);
            s_qh[g0][j] = dAba[j] + a0;
            s_qh[g1][j] = dAba[j] + a1;
        }
        __syncthreads();
        if (j < NS) {   // relu head (f64, R11 verbatim)
            double c00 = (double)s_c0[g0][j], c10 = (double)s_c1[g0][j];
            double c01 = (double)s_c0[g1][j], c11 = (double)s_c1[g1][j];
            double acc0 = 0.0, acc1 = 0.0;
            for (int h = 0; h < NH; ++h) {
                double A0 = dA0a[h], A1 = dA1a[h], v = (double)t_va[h];
                double p0 = fma(c00, A0, fma(c10, A1, s_qh[g0][h]));
                double p1 = fma(c01, A0, fma(c11, A1, s_qh[g1][h]));
                acc0 = fma(fmax(p0, 0.0), v, acc0);
                acc1 = fma(fmax(p1, 0.0), v, acc1);
            }
            s_lg[g0][j] = (float)acc0;
            s_lg[g1][j] = (float)acc1;
        }
        __syncthreads();
        if (j < 16) {
            float m0 = NEGF, m1 = NEGF;
            for (int s = j; s < NS; s += 16) { m0 = fmaxf(m0, s_lg[g0][s]); m1 = fmaxf(m1, s_lg[g1][s]); }
            s_red[g0][j] = m0; s_red[g1][j] = m1;
        }
        __syncthreads();
        if (tid < GPB) {
            float m = NEGF;
            for (int i = 0; i < 16; ++i) m = fmaxf(m, s_red[tid][i]);
            s_mx[tid] = m;
        }
        __syncthreads();
        if (j < NS) {
            s_a[g0][j] = (float)exp((double)s_lg[g0][j] - (double)s_mx[g0]);
            s_a[g1][j] = (float)exp((double)s_lg[g1][j] - (double)s_mx[g1]);
        }
        __syncthreads();
        if (j < 16) {
            double t0 = 0.0, t1 = 0.0;
            for (int s = j; s < NS; s += 16) { t0 += (double)s_a[g0][s]; t1 += (double)s_a[g1][s]; }
            s_redd[g0][j] = t0; s_redd[g1][j] = t1;
        }
        __syncthreads();
        if (tid < GPB) {
            double se = 0.0;
            for (int i = 0; i < 16; ++i) se += s_redd[tid][i];
            s_se[tid] = se;
        }
        __syncthreads();
        if (j < NS) {
            s_a[g0][j] = (float)((double)s_a[g0][j] / s_se[g0]);
            s_a[g1][j] = (float)((double)s_a[g1][j] / s_se[g1]);
        }
        __syncthreads();
        {   // context -> s_x[g][0..127] (f64 accum, R11 verbatim)
            float w0 = t_wi0[j], w1 = t_wi1[j], bb = t_bi[j];
            double a0 = 0.0, a1 = 0.0;
            for (int s = 0; s < NS; ++s) {
                float ih0 = fmaf(s_c0[g0][s], w0, fmaf(s_c1[g0][s], w1, bb));
                float ih1 = fmaf(s_c0[g1][s], w0, fmaf(s_c1[g1][s], w1, bb));
                a0 += (double)s_a[g0][s] * (double)ih0;
                a1 += (double)s_a[g1][s] * (double)ih1;
            }
            s_x[g0][j] = (float)a0;
            s_x[g1][j] = (float)a1;
        }
        __syncthreads();
        {   // pfc1: row i = tid, one read -> 4 batches (prefetch chunks)
            float r0, r1, r2, r3;
            dot4f<89>(pfc1_W + (size_t)tid * 356, s_x[0], s_x[1], s_x[2], s_x[3], r0, r1, r2, r3);
            float bb = pfc1_b[tid];
            s_fch[0][tid] = r0 + bb; s_fch[1][tid] = r1 + bb;
            s_fch[2][tid] = r2 + bb; s_fch[3][tid] = r3 + bb;
        }
        __syncthreads();
        {   // pfc2 (prefetch chunks)
            float r0, r1;
            dot2f<64>(pfc2_W + (size_t)j * 256, s_fch[g0], s_fch[g1], r0, r1);
            s_fco[g0][j] = r0 + pfc2_b[j];
            s_fco[g1][j] = r1 + pfc2_b[j];
        }
        __syncthreads();
        {   // q2 (ptr, f64 sequential, R11 order)
            double a0, a1;
            qcol2(ptr_W + (size_t)NH * NH + j, s_fco[g0], s_fco[g1], a0, a1);
            s_qh[g0][j] = dAbp[j] + a0;
            s_qh[g1][j] = dAbp[j] + a1;
        }
        __syncthreads();
        if (j < NS) {   // tanh pointer head (f64 pre, tanhf narrow — R11 verbatim)
            double c00 = (double)s_c0[g0][j], c10 = (double)s_c1[g0][j];
            double c01 = (double)s_c0[g1][j], c11 = (double)s_c1[g1][j];
            double acc0 = 0.0, acc1 = 0.0;
            for (int h = 0; h < NH; ++h) {
                double A0 = dA0p[h], A1 = dA1p[h], v = (double)t_vp[h];
                double p0 = fma(c00, A0, fma(c10, A1, s_qh[g0][h]));
                double p1 = fma(c01, A0, fma(c11, A1, s_qh[g1][h]));
                acc0 = fma((double)tanhf((float)p0), v, acc0);
                acc1 = fma((double)tanhf((float)p1), v, acc1);
            }
            s_lg[g0][j] = (float)acc0;
            s_lg[g1][j] = (float)acc1;
        }
        __syncthreads();
        if (j < 16) {   // masked segmented max of logits (exp stability only)
            float m0 = NEGF, m1 = NEGF;
            for (int s = j; s < NS; s += 16) {
                float v0 = (s_msk[g0][s] > 0.f) ? s_lg[g0][s] : NEGF;
                float v1 = (s_msk[g1][s] > 0.f) ? s_lg[g1][s] : NEGF;
                m0 = fmaxf(m0, v0);
                m1 = fmaxf(m1, v1);
            }
            s_red[g0][j] = m0; s_red[g1][j] = m1;
        }
        __syncthreads();
        if (tid < GPB) {
            float m = NEGF;
            for (int i = 0; i < 16; ++i) m = fmaxf(m, s_red[tid][i]);
            s_mx[tid] = m;
        }
        __syncthreads();
        if (j < NS) {   // masked exps, f64 exp narrowed to f32 (R11 verbatim)
            s_a[g0][j] = (s_msk[g0][j] > 0.f) ? (float)exp((double)s_lg[g0][j] - (double)s_mx[g0]) : 0.f;
            s_a[g1][j] = (s_msk[g1][j] > 0.f) ? (float)exp((double)s_lg[g1][j] - (double)s_mx[g1]) : 0.f;
        }
        __syncthreads();
        if (j < 16) {   // argmax over f32 EXPS, first-occurrence ties (R11 verbatim)
            float m0 = -1.f, m1 = -1.f; int i0 = 0, i1 = 0;
            double t0 = 0.0, t1 = 0.0;
            for (int s = j; s < NS; s += 16) {
                float a0v = s_a[g0][s], a1v = s_a[g1][s];
                t0 += (double)a0v; t1 += (double)a1v;
                if (a0v > m0) { m0 = a0v; i0 = s; }
                if (a1v > m1) { m1 = a1v; i1 = s; }
            }
            s_red[g0][j] = m0; s_ri[g0][j] = i0; s_redd[g0][j] = t0;
            s_red[g1][j] = m1; s_ri[g1][j] = i1; s_redd[g1][j] = t1;
        }
        __syncthreads();
        if (tid < GPB) {   // fold + logp + outputs + carry (R11 verbatim)
            int g = tid, b = bbase + g;
            float m = -1.f; int mi = NS; double se = 0.0;
            for (int i = 0; i < 16; ++i) {
                se += s_redd[g][i];
                float v = s_red[g][i]; int vi = s_ri[g][i];
                if (v > m || (v == m && vi < mi)) { m = v; mi = vi; }
            }
            int pt = sol2[b * NS + t];
            double logp = log((double)s_a[g][pt] / se);
            out[OUT_TI + b * NS + t]             = (float)mi;
            out[OUT_LP + b * (NS - 1) + (t - 1)] = (float)logp;
            s_msk[g][pt] = 0.f;
            s_rc0[g] = s_c0[g][pt];
            s_rc1[g] = s_c1[g][pt];
        }
        __syncthreads();
    }
}

extern "C" void kernel_launch(void* const* d_in, const int* in_sizes, int n_in,
                              void* d_out, int out_size, void* d_ws, size_t ws_size,
                              hipStream_t stream)
{
    (void)in_sizes; (void)n_in; (void)out_size; (void)d_ws; (void)ws_size;
    vae_v13<<<NBLK, NTHR, 0, stream>>>(
        (const float*)d_in[0], (const int*)d_in[1], (const int*)d_in[2], (const float*)d_in[3],
        (const float*)d_in[4], (const float*)d_in[5], (const float*)d_in[6], (const float*)d_in[7],
        (const float*)d_in[8], (const float*)d_in[9], (const float*)d_in[10], (const float*)d_in[11],
        (const float*)d_in[12], (const float*)d_in[13], (const float*)d_in[14], (const float*)d_in[15],
        (const float*)d_in[16], (const float*)d_in[17], (const float*)d_in[18], (const float*)d_in[19],
        (const float*)d_in[20], (const float*)d_in[21], (const float*)d_in[22], (const float*)d_in[23],
        (const float*)d_in[24], (const float*)d_in[25], (const float*)d_in[26], (const float*)d_in[27],
        (float*)d_out);
}